// Round 1
// baseline (65.577 us; speedup 1.0000x reference)
//
#include <hip/hip_runtime.h>

#define N 4096
#define ROWS_PER_BLOCK 16
#define NBLOCKS (N / ROWS_PER_BLOCK)   // 256 blocks = 1 per CU
#define THREADS 1024                   // 16 waves/block = 4 waves/SIMD
#define R 4                            // rows per thread (LDS reuse factor)
#define CCHUNKS (THREADS / R)          // 256 j-chunks
#define JPT (N / CCHUNKS)              // 16 j-iterations per thread
#define NOTCH_THRESH 2.0f

// Full-matrix pairwise penalty; upper-triangle sum recovered as
// (full_sum - 4*N) * 0.5  (diagonal pair has d=0 -> penalty^2 = 4).
//
// tile[j] stores box EDGES {Lx, Rx, Ly, Ry} (L = center - size/2) so the
// per-pair gap is  max(L_i - R_j, L_j - R_i, 0)  -- two subs + a max3
// (no fabs, no half-width add): 10 VALU/pair if v_max3 fuses.
//
// 1024 threads/block: 4 waves/SIMD to hide ds_read + dependent-FMA latency
// (previous 512-thread config was 2 waves/SIMD and latency-bound at ~13%
// of the VALU roofline).
__global__ __launch_bounds__(THREADS) void notch_main(
    const float* __restrict__ pos,
    const float* __restrict__ sx,
    const float* __restrict__ sy,
    float* __restrict__ partial)
{
    __shared__ float4 tile[N];                 // 64 KB: {Lx, Rx, Ly, Ry}
    __shared__ float red[THREADS / 64];

    const int tid = threadIdx.x;

    // Stage edges into LDS (coalesced global reads; inputs are tiny/L2-hot)
    for (int j = tid; j < N; j += THREADS) {
        const float x  = pos[j];
        const float y  = pos[N + j];           // NUM_PHYS == N
        const float hx = 0.5f * sx[j];
        const float hy = 0.5f * sy[j];
        float4 t;
        t.x = x - hx;   // Lx
        t.y = x + hx;   // Rx
        t.z = y - hy;   // Ly
        t.w = y + hy;   // Ry
        tile[j] = t;
    }
    __syncthreads();

    // thread -> (row group g of R rows, j-chunk c)
    const int g  = tid & (R - 1);              // 0..3
    const int c  = tid >> 2;                   // 0..255; 4-lane broadcast groups
    const int i0 = blockIdx.x * ROWS_PER_BLOCK + g * R;

    const float4 me0 = tile[i0 + 0];
    const float4 me1 = tile[i0 + 1];
    const float4 me2 = tile[i0 + 2];
    const float4 me3 = tile[i0 + 3];

    float a0 = 0.0f, a1 = 0.0f, a2 = 0.0f, a3 = 0.0f;

#define PAIR(me, acc) {                                                  \
        float gx = fmaxf(fmaxf(me.x - t.y, t.x - me.y), 0.0f);           \
        float gy = fmaxf(fmaxf(me.z - t.w, t.z - me.w), 0.0f);           \
        float p  = fmaxf(NOTCH_THRESH - (gx + gy), 0.0f);                \
        acc = fmaf(p, p, acc); }

    // j = jj*256 + c: wave reads 16 consecutive float4 slots (4-lane
    // broadcast each, 2-way bank aliasing = free). ds_read_b128 with
    // immediate offsets after unroll (stride 4096 B).
    #pragma unroll 4
    for (int jj = 0; jj < JPT; ++jj) {
        const float4 t = tile[jj * CCHUNKS + c];
        PAIR(me0, a0)
        PAIR(me1, a1)
        PAIR(me2, a2)
        PAIR(me3, a3)
    }
#undef PAIR

    float acc = (a0 + a1) + (a2 + a3);

    // Deterministic reduction: wave shuffle -> LDS -> per-block partial
    for (int off = 32; off > 0; off >>= 1)
        acc += __shfl_down(acc, off, 64);
    const int wave = tid >> 6;
    const int lane = tid & 63;
    if (lane == 0) red[wave] = acc;
    __syncthreads();
    if (tid == 0) {
        float s = 0.0f;
        #pragma unroll
        for (int w = 0; w < THREADS / 64; ++w) s += red[w];
        partial[blockIdx.x] = s;
    }
}

__global__ __launch_bounds__(256) void notch_final(
    const float* __restrict__ partial, float* __restrict__ out)
{
    __shared__ float red[4];
    const int tid = threadIdx.x;
    float v = partial[tid];   // exactly 256 partials
    for (int off = 32; off > 0; off >>= 1)
        v += __shfl_down(v, off, 64);
    if ((tid & 63) == 0) red[tid >> 6] = v;
    __syncthreads();
    if (tid == 0) {
        const float total = red[0] + red[1] + red[2] + red[3];
        out[0] = (total - 4.0f * (float)N) * 0.5f;
    }
}

extern "C" void kernel_launch(void* const* d_in, const int* in_sizes, int n_in,
                              void* d_out, int out_size, void* d_ws, size_t ws_size,
                              hipStream_t stream) {
    const float* pos = (const float*)d_in[0];
    // d_in[1] = macro_mask (unused by the reference computation)
    const float* sx  = (const float*)d_in[2];
    const float* sy  = (const float*)d_in[3];
    float* out     = (float*)d_out;
    float* partial = (float*)d_ws;   // 256 floats of scratch

    notch_main<<<NBLOCKS, THREADS, 0, stream>>>(pos, sx, sy, partial);
    notch_final<<<1, 256, 0, stream>>>(partial, out);
}